// Round 4
// baseline (58.287 us; speedup 1.0000x reference)
//
#include <hip/hip_runtime.h>
#include <math.h>

#define B_DIM 4096
#define N_DIM 8192
#define K_ROWS 16               // output rows per block
#define NBLK (B_DIM / K_ROWS)   // 256 blocks = 1 per CU

__constant__ const float kCommission = 0.0025f;
__constant__ const float kInterest   = 8e-05f;

// ---------------------------------------------------------------------------
// Finalize over the 4096 rewards, run by ONE 256-thread block (the last one
// to finish the main phase). 16 rewards per thread.
//   loss = -mean(log r); pv = exp(sum log r);
//   SR = (mean-1)/std(ddof=1) in double (std ~ 2.5e-4: cancellation-sensitive);
//   MDD via log-space prefix-sum / prefix-max (exp is monotone).
// ---------------------------------------------------------------------------
__device__ void finalize_256(const float* __restrict__ reward, float* __restrict__ out) {
    const int PER = 16;
    const int tid  = threadIdx.x;
    const int lane = tid & 63, wave = tid >> 6;

    float r[PER], lc[PER];
    float csum = 0.f;
    #pragma unroll
    for (int j = 0; j < PER; ++j) {
        r[j] = reward[tid * PER + j];
        csum += logf(r[j]);
        lc[j] = csum;                       // inclusive prefix within chunk
    }

    // ---- block inclusive scan (add) of per-thread chunk log-sums ----
    float v = csum;
    #pragma unroll
    for (int off = 1; off < 64; off <<= 1) {
        float t = __shfl_up(v, off);
        if (lane >= off) v += t;
    }
    __shared__ float wsum[4], woff[5];
    if (lane == 63) wsum[wave] = v;
    __syncthreads();
    if (tid == 0) {
        float acc = 0.f;
        for (int i = 0; i < 4; ++i) { woff[i] = acc; acc += wsum[i]; }
        woff[4] = acc;
    }
    __syncthreads();
    float ev = __shfl_up(v, 1);
    if (lane == 0) ev = 0.f;
    const float excl = woff[wave] + ev;
    float S[PER];
    #pragma unroll
    for (int j = 0; j < PER; ++j) S[j] = excl + lc[j];
    const float total_logs = woff[4];

    // ---- block prefix-max over S ----
    float rm = -INFINITY;
    float cmax[PER];
    #pragma unroll
    for (int j = 0; j < PER; ++j) { rm = fmaxf(rm, S[j]); cmax[j] = rm; }
    float mv = rm;
    #pragma unroll
    for (int off = 1; off < 64; off <<= 1) {
        float t = __shfl_up(mv, off);
        if (lane >= off) mv = fmaxf(mv, t);
    }
    __shared__ float wmax[4], wmoff[4];
    if (lane == 63) wmax[wave] = mv;
    __syncthreads();
    if (tid == 0) {
        float acc = -INFINITY;
        for (int i = 0; i < 4; ++i) { wmoff[i] = acc; acc = fmaxf(acc, wmax[i]); }
    }
    __syncthreads();
    float emv = __shfl_up(mv, 1);
    if (lane == 0) emv = -INFINITY;
    const float mexcl = fmaxf(wmoff[wave], emv);

    float ddmax = 0.f;
    #pragma unroll
    for (int j = 0; j < PER; ++j) {
        float M = fmaxf(mexcl, cmax[j]);
        ddmax = fmaxf(ddmax, 1.0f - expf(S[j] - M));
    }
    #pragma unroll
    for (int off = 32; off; off >>= 1) ddmax = fmaxf(ddmax, __shfl_down(ddmax, off));
    __shared__ float wdd[4];
    if (lane == 0) wdd[wave] = ddmax;

    // ---- double-precision two-pass mean/var for SR ----
    double sr_ = 0.0;
    #pragma unroll
    for (int j = 0; j < PER; ++j) sr_ += (double)r[j];
    #pragma unroll
    for (int off = 32; off; off >>= 1) sr_ += __shfl_down(sr_, off);
    __shared__ double wsr[4];
    if (lane == 0) wsr[wave] = sr_;
    __syncthreads();
    __shared__ double mean_sh;
    if (tid == 0) mean_sh = (wsr[0] + wsr[1] + wsr[2] + wsr[3]) / (double)B_DIM;
    __syncthreads();
    const double mean = mean_sh;
    double sq = 0.0;
    #pragma unroll
    for (int j = 0; j < PER; ++j) { double dd = (double)r[j] - mean; sq += dd * dd; }
    #pragma unroll
    for (int off = 32; off; off >>= 1) sq += __shfl_down(sq, off);
    __shared__ double wsq[4];
    if (lane == 0) wsq[wave] = sq;
    __syncthreads();

    if (tid == 0) {
        double s = wsq[0] + wsq[1] + wsq[2] + wsq[3];
        double var = s / (double)(B_DIM - 1);
        double SR = (mean - 1.0) / sqrt(var);
        float mdd = fmaxf(fmaxf(wdd[0], wdd[1]), fmaxf(wdd[2], wdd[3]));
        out[0] = -total_logs / (float)B_DIM;   // loss
        out[1] = expf(total_logs);             // portfolio_value = prod(reward)
        out[2] = (float)SR;                    // SR
        out[3] = mdd;                          // MDD
    }
}

// ---------------------------------------------------------------------------
// Fused kernel: block i produces reward[16i .. 16i+15] (software-pipelined,
// prefetch-before-reduce, double-buffered LDS reduce = 1 barrier/row).
// The LAST block (device-scope atomic ticket) then runs finalize_256.
// ---------------------------------------------------------------------------
__global__ __launch_bounds__(256) void fused_all_kernel(const float* __restrict__ w,
                                                        const float* __restrict__ y,
                                                        float* __restrict__ reward_out,
                                                        int* __restrict__ ticket,
                                                        float* __restrict__ out) {
    const int s    = blockIdx.x * K_ROWS;
    const int tid  = threadIdx.x;
    const int lane = tid & 63, wave = tid >> 6;
    __shared__ float red[2][4][3];

    float4 wv[8], yv[8];      // staging registers (row in flight)
    float4 e_prev[8];         // previous row's element rewards
    float  inv_dprev;

    // ---- prep: boundary row s-1 (block 0 uses row 0; its comm is discarded) ----
    {
        const int rp = (s == 0) ? 0 : s - 1;
        const float4* wb = (const float4*)(w + (size_t)rp * N_DIM);
        const float4* yb = (const float4*)(y + (size_t)rp * N_DIM);
        #pragma unroll
        for (int j = 0; j < 8; ++j) wv[j] = wb[tid + 256 * j];
        #pragma unroll
        for (int j = 0; j < 8; ++j) yv[j] = yb[tid + 256 * j];

        float d = 0.f;
        #pragma unroll
        for (int j = 0; j < 8; ++j) {
            float4 ev;
            ev.x = wv[j].x * yv[j].x; ev.y = wv[j].y * yv[j].y;
            ev.z = wv[j].z * yv[j].z; ev.w = wv[j].w * yv[j].w;
            d += (ev.x + ev.y) + (ev.z + ev.w);
            e_prev[j] = ev;
        }

        // prefetch row s while the reduction runs
        const float4* wc = (const float4*)(w + (size_t)s * N_DIM);
        const float4* yc = (const float4*)(y + (size_t)s * N_DIM);
        #pragma unroll
        for (int j = 0; j < 8; ++j) wv[j] = wc[tid + 256 * j];
        #pragma unroll
        for (int j = 0; j < 8; ++j) yv[j] = yc[tid + 256 * j];

        #pragma unroll
        for (int off = 32; off; off >>= 1) d += __shfl_down(d, off);
        if (lane == 0) red[0][wave][0] = d;
        __syncthreads();
        inv_dprev = 1.0f / ((red[0][0][0] + red[0][1][0]) + (red[0][2][0] + red[0][3][0]));
    }

    // ---- main phases ----
    #pragma unroll 1
    for (int k = 0; k < K_ROWS; ++k) {
        const int r = s + k;

        float d = 0.f, it = 0.f, cm = 0.f;
        #pragma unroll
        for (int j = 0; j < 8; ++j) {
            float4 ev;
            ev.x = wv[j].x * yv[j].x; ev.y = wv[j].y * yv[j].y;
            ev.z = wv[j].z * yv[j].z; ev.w = wv[j].w * yv[j].w;
            d  += (ev.x + ev.y) + (ev.z + ev.w);
            it += (fminf(ev.x, 0.f) + fminf(ev.y, 0.f)) +
                  (fminf(ev.z, 0.f) + fminf(ev.w, 0.f));
            cm += (fabsf(fmaf(e_prev[j].x, inv_dprev, -wv[j].x)) +
                   fabsf(fmaf(e_prev[j].y, inv_dprev, -wv[j].y))) +
                  (fabsf(fmaf(e_prev[j].z, inv_dprev, -wv[j].z)) +
                   fabsf(fmaf(e_prev[j].w, inv_dprev, -wv[j].w)));
            e_prev[j] = ev;
        }

        // issue next row's loads before the reduction (HBM overlaps shfl chain)
        if (k + 1 < K_ROWS) {
            const float4* wn = (const float4*)(w + (size_t)(r + 1) * N_DIM);
            const float4* yn = (const float4*)(y + (size_t)(r + 1) * N_DIM);
            #pragma unroll
            for (int j = 0; j < 8; ++j) wv[j] = wn[tid + 256 * j];
            #pragma unroll
            for (int j = 0; j < 8; ++j) yv[j] = yn[tid + 256 * j];
        }

        #pragma unroll
        for (int off = 32; off; off >>= 1) {
            d  += __shfl_down(d,  off);
            it += __shfl_down(it, off);
            cm += __shfl_down(cm, off);
        }
        const int pb = (k + 1) & 1;
        if (lane == 0) { red[pb][wave][0] = d; red[pb][wave][1] = it; red[pb][wave][2] = cm; }
        __syncthreads();
        const float dot_r = (red[pb][0][0] + red[pb][1][0]) + (red[pb][2][0] + red[pb][3][0]);
        const float int_r = ((red[pb][0][1] + red[pb][1][1]) + (red[pb][2][1] + red[pb][3][1])) * kInterest;
        const float comm  = (red[pb][0][2] + red[pb][1][2]) + (red[pb][2][2] + red[pb][3][2]);
        const float pc = (r == 0) ? 1.0f : fmaf(-comm, kCommission, 1.0f);
        if (tid == 0) reward_out[r] = dot_r * pc + int_r;
        inv_dprev = 1.0f / dot_r;
    }

    // ---- last-block ticket: run finalize once all rewards are visible ----
    __shared__ int is_last;
    if (tid == 0) {
        __threadfence();                      // release this block's reward stores
        int prev = atomicAdd(ticket, 1);      // device-scope by default on CDNA
        is_last = (prev == NBLK - 1) ? 1 : 0;
    }
    __syncthreads();
    if (is_last) {
        __threadfence();                      // acquire: no stale reward lines
        finalize_256(reward_out, out);
    }
}

// ---------------------------------------------------------------------------
extern "C" void kernel_launch(void* const* d_in, const int* in_sizes, int n_in,
                              void* d_out, int out_size, void* d_ws, size_t ws_size,
                              hipStream_t stream) {
    const float* w = (const float*)d_in[0];   // (B,1,N)
    const float* y = (const float*)d_in[1];   // (B,N,1)
    float* out = (float*)d_out;

    float* rew    = (float*)d_ws;             // B_DIM floats
    int*   ticket = (int*)((char*)d_ws + B_DIM * sizeof(float));

    hipMemsetAsync(ticket, 0, sizeof(int), stream);   // capture-safe memset node
    fused_all_kernel<<<NBLK, 256, 0, stream>>>(w, y, rew, ticket, out);
}

// Round 5
// 49.875 us; speedup vs baseline: 1.1687x; 1.1687x over previous
//
#include <hip/hip_runtime.h>
#include <math.h>

#define B_DIM 4096
#define N_DIM 8192
#define K_ROWS 16               // output rows per block
#define NBLK (B_DIM / K_ROWS)   // 256 blocks = 1 per CU

__constant__ const float kCommission = 0.0025f;
__constant__ const float kInterest   = 8e-05f;

// ---------------------------------------------------------------------------
// Fused kernel: block with (swizzled) group id g produces reward[16g..16g+15].
// Software-pipelined: consume staged regs -> partials; issue next row's loads
// BEFORE the shfl/LDS reduction so HBM delivery overlaps it. Double-buffered
// LDS reduce = 1 barrier/row.
// XCD swizzle: g = (bid%8)*32 + bid/8  ==> each XCD owns 32 consecutive row
// groups, so the boundary row shared by groups g,g+1 hits the same XCD-L2.
// ---------------------------------------------------------------------------
__global__ __launch_bounds__(256) void fused_reward_kernel(const float* __restrict__ w,
                                                           const float* __restrict__ y,
                                                           float* __restrict__ reward_out) {
    const int g    = (blockIdx.x % 8) * 32 + blockIdx.x / 8;   // bijective on 256
    const int s    = g * K_ROWS;
    const int tid  = threadIdx.x;
    const int lane = tid & 63, wave = tid >> 6;
    __shared__ float red[2][4][3];

    float4 wv[8], yv[8];      // staging registers (row in flight)
    float4 e_prev[8];         // previous row's element rewards
    float  inv_dprev;

    // ---- prep: boundary row s-1 (block 0 uses row 0; its comm is discarded) ----
    {
        const int rp = (s == 0) ? 0 : s - 1;
        const float4* wb = (const float4*)(w + (size_t)rp * N_DIM);
        const float4* yb = (const float4*)(y + (size_t)rp * N_DIM);
        #pragma unroll
        for (int j = 0; j < 8; ++j) wv[j] = wb[tid + 256 * j];
        #pragma unroll
        for (int j = 0; j < 8; ++j) yv[j] = yb[tid + 256 * j];

        float d = 0.f;
        #pragma unroll
        for (int j = 0; j < 8; ++j) {
            float4 ev;
            ev.x = wv[j].x * yv[j].x; ev.y = wv[j].y * yv[j].y;
            ev.z = wv[j].z * yv[j].z; ev.w = wv[j].w * yv[j].w;
            d += (ev.x + ev.y) + (ev.z + ev.w);
            e_prev[j] = ev;
        }

        // prefetch row s while the reduction runs
        const float4* wc = (const float4*)(w + (size_t)s * N_DIM);
        const float4* yc = (const float4*)(y + (size_t)s * N_DIM);
        #pragma unroll
        for (int j = 0; j < 8; ++j) wv[j] = wc[tid + 256 * j];
        #pragma unroll
        for (int j = 0; j < 8; ++j) yv[j] = yc[tid + 256 * j];

        #pragma unroll
        for (int off = 32; off; off >>= 1) d += __shfl_down(d, off);
        if (lane == 0) red[0][wave][0] = d;
        __syncthreads();
        inv_dprev = 1.0f / ((red[0][0][0] + red[0][1][0]) + (red[0][2][0] + red[0][3][0]));
    }

    // ---- main phases: rows s .. s+K_ROWS-1, pipelined ----
    #pragma unroll 1
    for (int k = 0; k < K_ROWS; ++k) {
        const int r = s + k;

        float d = 0.f, it = 0.f, cm = 0.f;
        #pragma unroll
        for (int j = 0; j < 8; ++j) {
            float4 ev;
            ev.x = wv[j].x * yv[j].x; ev.y = wv[j].y * yv[j].y;
            ev.z = wv[j].z * yv[j].z; ev.w = wv[j].w * yv[j].w;
            d  += (ev.x + ev.y) + (ev.z + ev.w);
            it += (fminf(ev.x, 0.f) + fminf(ev.y, 0.f)) +
                  (fminf(ev.z, 0.f) + fminf(ev.w, 0.f));
            cm += (fabsf(fmaf(e_prev[j].x, inv_dprev, -wv[j].x)) +
                   fabsf(fmaf(e_prev[j].y, inv_dprev, -wv[j].y))) +
                  (fabsf(fmaf(e_prev[j].z, inv_dprev, -wv[j].z)) +
                   fabsf(fmaf(e_prev[j].w, inv_dprev, -wv[j].w)));
            e_prev[j] = ev;
        }

        // issue next row's loads before the reduction (HBM overlaps shfl chain)
        if (k + 1 < K_ROWS) {
            const float4* wn = (const float4*)(w + (size_t)(r + 1) * N_DIM);
            const float4* yn = (const float4*)(y + (size_t)(r + 1) * N_DIM);
            #pragma unroll
            for (int j = 0; j < 8; ++j) wv[j] = wn[tid + 256 * j];
            #pragma unroll
            for (int j = 0; j < 8; ++j) yv[j] = yn[tid + 256 * j];
        }

        #pragma unroll
        for (int off = 32; off; off >>= 1) {
            d  += __shfl_down(d,  off);
            it += __shfl_down(it, off);
            cm += __shfl_down(cm, off);
        }
        const int pb = (k + 1) & 1;   // double-buffer: 1 barrier per phase
        if (lane == 0) { red[pb][wave][0] = d; red[pb][wave][1] = it; red[pb][wave][2] = cm; }
        __syncthreads();
        const float dot_r = (red[pb][0][0] + red[pb][1][0]) + (red[pb][2][0] + red[pb][3][0]);
        const float int_r = ((red[pb][0][1] + red[pb][1][1]) + (red[pb][2][1] + red[pb][3][1])) * kInterest;
        const float comm  = (red[pb][0][2] + red[pb][1][2]) + (red[pb][2][2] + red[pb][3][2]);
        const float pc = (r == 0) ? 1.0f : fmaf(-comm, kCommission, 1.0f);
        if (tid == 0) reward_out[r] = dot_r * pc + int_r;
        inv_dprev = 1.0f / dot_r;
    }
}

// ---------------------------------------------------------------------------
// Finalize (round-3 passing version): 1 block, 1024 threads, 4 rewards/thread.
//   loss = -mean(log r); pv = exp(sum log r);
//   SR = (mean-1)/std(ddof=1) in double (std ~2.5e-4, cancellation-sensitive);
//   MDD via log-space prefix-sum / prefix-max (exp monotone).
// ---------------------------------------------------------------------------
__global__ __launch_bounds__(1024) void finalize_kernel(const float* __restrict__ reward,
                                                        float* __restrict__ out) {
    const int PER = 4;
    const int tid = threadIdx.x;
    const int lane = tid & 63, wave = tid >> 6;

    float r[PER], lc[PER];
    float csum = 0.f;
    #pragma unroll
    for (int j = 0; j < PER; ++j) {
        r[j] = reward[tid * PER + j];
        csum += logf(r[j]);
        lc[j] = csum;
    }

    // block inclusive scan of per-thread log sums
    float v = csum;
    #pragma unroll
    for (int off = 1; off < 64; off <<= 1) {
        float t = __shfl_up(v, off);
        if (lane >= off) v += t;
    }
    __shared__ float wsum[16];
    __shared__ float woff[17];
    if (lane == 63) wsum[wave] = v;
    __syncthreads();
    if (tid == 0) {
        float acc = 0.f;
        for (int i = 0; i < 16; ++i) { woff[i] = acc; acc += wsum[i]; }
        woff[16] = acc;
    }
    __syncthreads();
    float ev = __shfl_up(v, 1);
    if (lane == 0) ev = 0.f;
    const float excl = woff[wave] + ev;
    float S[PER];
    #pragma unroll
    for (int j = 0; j < PER; ++j) S[j] = excl + lc[j];
    const float total_logs = woff[16];

    // block prefix-max over S
    float rm = -INFINITY;
    float cmax[PER];
    #pragma unroll
    for (int j = 0; j < PER; ++j) { rm = fmaxf(rm, S[j]); cmax[j] = rm; }
    float mv = rm;
    #pragma unroll
    for (int off = 1; off < 64; off <<= 1) {
        float t = __shfl_up(mv, off);
        if (lane >= off) mv = fmaxf(mv, t);
    }
    __shared__ float wmax[16];
    __shared__ float wmoff[16];
    if (lane == 63) wmax[wave] = mv;
    __syncthreads();
    if (tid == 0) {
        float acc = -INFINITY;
        for (int i = 0; i < 16; ++i) { wmoff[i] = acc; acc = fmaxf(acc, wmax[i]); }
    }
    __syncthreads();
    float emv = __shfl_up(mv, 1);
    if (lane == 0) emv = -INFINITY;
    const float mexcl = fmaxf(wmoff[wave], emv);

    float ddmax = 0.f;
    #pragma unroll
    for (int j = 0; j < PER; ++j) {
        float M = fmaxf(mexcl, cmax[j]);
        ddmax = fmaxf(ddmax, 1.0f - expf(S[j] - M));
    }
    #pragma unroll
    for (int off = 32; off; off >>= 1) ddmax = fmaxf(ddmax, __shfl_down(ddmax, off));
    __shared__ float wdd[16];
    if (lane == 0) wdd[wave] = ddmax;

    // double-precision two-pass mean/var for SR
    double sr_ = 0.0;
    #pragma unroll
    for (int j = 0; j < PER; ++j) sr_ += (double)r[j];
    #pragma unroll
    for (int off = 32; off; off >>= 1) sr_ += __shfl_down(sr_, off);
    __shared__ double wsr[16];
    if (lane == 0) wsr[wave] = sr_;
    __syncthreads();
    __shared__ double mean_sh;
    if (tid == 0) {
        double sm = 0.0;
        for (int i = 0; i < 16; ++i) sm += wsr[i];
        mean_sh = sm / (double)B_DIM;
    }
    __syncthreads();
    const double mean = mean_sh;
    double sq = 0.0;
    #pragma unroll
    for (int j = 0; j < PER; ++j) { double dd = (double)r[j] - mean; sq += dd * dd; }
    #pragma unroll
    for (int off = 32; off; off >>= 1) sq += __shfl_down(sq, off);
    __shared__ double wsq[16];
    if (lane == 0) wsq[wave] = sq;
    __syncthreads();

    if (tid == 0) {
        double sm = 0.0;
        for (int i = 0; i < 16; ++i) sm += wsq[i];
        double var = sm / (double)(B_DIM - 1);
        double SR = (mean - 1.0) / sqrt(var);
        float mdd = 0.f;
        for (int i = 0; i < 16; ++i) mdd = fmaxf(mdd, wdd[i]);
        out[0] = -total_logs / (float)B_DIM;
        out[1] = expf(total_logs);
        out[2] = (float)SR;
        out[3] = mdd;
    }
}

// ---------------------------------------------------------------------------
extern "C" void kernel_launch(void* const* d_in, const int* in_sizes, int n_in,
                              void* d_out, int out_size, void* d_ws, size_t ws_size,
                              hipStream_t stream) {
    const float* w = (const float*)d_in[0];   // (B,1,N)
    const float* y = (const float*)d_in[1];   // (B,N,1)
    float* out = (float*)d_out;
    float* rew = (float*)d_ws;                // B floats

    fused_reward_kernel<<<NBLK, 256, 0, stream>>>(w, y, rew);
    finalize_kernel<<<1, 1024, 0, stream>>>(rew, out);
}